// Round 5
// baseline (346.495 us; speedup 1.0000x reference)
//
#include <hip/hip_runtime.h>
#include <hip/hip_bf16.h>
#include <stdint.h>

// B=4, L=1024, C=768, H=12, D=64.  All inputs/outputs fp32.
// Pipeline (all-MFMA bf16, fp32 accumulate):
//   c1: cast x, w_qkv, w_proj -> bf16 ws (single fused launch)
//   k1: qkv GEMM  [4096x768]@[2304x768]^T (128x128 tile, dbuf prefetch, XCD-swizzled)
//       -> scatter q(pre*0.125),k [bh][l][d], v^T [bh][d][l]  (bf16)
//   k2: attention per (bh, 32 rows): 8 waves, swapped QK^T -> online register softmax
//       (1 publish, 2 barriers) -> out1 fp32 nt-stores + normalized bf16 S in LDS
//       -> PV MFMA -> attn_o.  XCD-swizzled 1D grid; setprio around MFMA clusters.
//   k3: proj GEMM  [4096x768]@[768x768]^T + bias (128x64 tile, XCD-swizzled) -> out0 fp32

typedef __attribute__((ext_vector_type(8))) short short8;
typedef __attribute__((ext_vector_type(4))) float floatx4;

#define MFMA16(A_, B_, C_) __builtin_amdgcn_mfma_f32_16x16x32_bf16((A_), (B_), (C_), 0, 0, 0)

__device__ __forceinline__ unsigned short f2bf(float f) {
  unsigned u = __builtin_bit_cast(unsigned, f);
  u += 0x7FFFu + ((u >> 16) & 1u);   // round-to-nearest-even
  return (unsigned short)(u >> 16);
}
__device__ __forceinline__ float bf2f(unsigned short u) {
  return __builtin_bit_cast(float, (unsigned)u << 16);
}

// ---------------- fused cast fp32 -> bf16 (x, w_qkv, w_proj; contiguous dst) ----------------
__global__ __launch_bounds__(256) void cast3_kernel(const float* __restrict__ x,
                                                    const float* __restrict__ wq,
                                                    const float* __restrict__ wp,
                                                    unsigned short* __restrict__ dst) {
  const int NX = 3145728, NWQ = 1769472;  // region boundaries are block-aligned
  int i = (blockIdx.x * 256 + threadIdx.x) * 4;
  const float* src;
  int off;
  if (i < NX) { src = x; off = i; }
  else if (i < NX + NWQ) { src = wq; off = i - NX; }
  else { src = wp; off = i - NX - NWQ; }
  float4 v = *(const float4*)(src + off);
  ushort4 o;
  o.x = f2bf(v.x); o.y = f2bf(v.y); o.z = f2bf(v.z); o.w = f2bf(v.w);
  *(ushort4*)(dst + i) = o;
}

// ---------------- bf16 MFMA GEMM: C[M][N] = A[M][K] @ Bm[N][K]^T ----------------
// tile 128xBN, BK=32, 256 threads = 4 waves.  Wave (wm,wn) owns a 64x(BN/2) quadrant.
// Double-buffered LDS; next K-tile's global_load_lds issued BEFORE compute of current.
// 1D grid, bijective XCD swizzle (nb = 8*chunk): each XCD owns `chunk` consecutive
// tiles (row-major) -> A-panels + B fit one XCD L2.
// EPI 0: qkv scatter epilogue (BN=128 only).  EPI 1: fp32 C + bias epilogue (nt store).
template <int EPI, int BN>
__global__ __launch_bounds__(256) void gemm_bt(
    const unsigned short* __restrict__ A, const unsigned short* __restrict__ Bm,
    const float* __restrict__ bias,
    unsigned short* __restrict__ q_ws, unsigned short* __restrict__ k_ws,
    unsigned short* __restrict__ vt_ws, float* __restrict__ Cout,
    int M, int N, int K, int nbx, int chunk) {
  constexpr int NJ = BN / 32;  // N-frags per wave (4 or 2)
  constexpr int QN = BN / 2;   // wave quadrant N-size (64 or 32)
  __shared__ __align__(16) unsigned short Al[2][128 * 32];
  __shared__ __align__(16) unsigned short Bl[2][BN * 32];
  const int tid = threadIdx.x;
  const int lane = tid & 63, wave = tid >> 6;
  const int q = lane >> 4, lm = lane & 15;
  const int wm = wave >> 1, wn = wave & 1;
  const int flat = blockIdx.x;
  const int swz = (flat & 7) * chunk + (flat >> 3);
  const int m0 = (swz / nbx) * 128, n0 = (swz % nbx) * BN;

  floatx4 acc[4][NJ];
#pragma unroll
  for (int i = 0; i < 4; ++i)
#pragma unroll
    for (int j = 0; j < NJ; ++j) acc[i][j] = (floatx4){0.f, 0.f, 0.f, 0.f};

  auto stage = [&](int k0, int buf) {
#pragma unroll
    for (int it = 0; it < 2; ++it) {
      int idx = tid + it * 256;
      int row = idx >> 2, ch = idx & 3;
      const unsigned short* ga = A + (size_t)(m0 + row) * K + k0 + ch * 8;
      __builtin_amdgcn_global_load_lds(
          (const __attribute__((address_space(1))) unsigned int*)ga,
          (__attribute__((address_space(3))) unsigned int*)(&Al[buf][0] + idx * 8), 16, 0, 0);
    }
#pragma unroll
    for (int it = 0; it < BN / 64; ++it) {
      int idx = tid + it * 256;
      int row = idx >> 2, ch = idx & 3;
      const unsigned short* gb = Bm + (size_t)(n0 + row) * K + k0 + ch * 8;
      __builtin_amdgcn_global_load_lds(
          (const __attribute__((address_space(1))) unsigned int*)gb,
          (__attribute__((address_space(3))) unsigned int*)(&Bl[buf][0] + idx * 8), 16, 0, 0);
    }
  };

  stage(0, 0);
  __syncthreads();
  int cur = 0;
  for (int k0 = 0; k0 < K; k0 += 32) {
    if (k0 + 32 < K) stage(k0 + 32, cur ^ 1);  // prefetch next tile, in flight during MFMA
    short8 af[4], bfr[NJ];
#pragma unroll
    for (int t = 0; t < 4; ++t)
      af[t] = *(const short8*)(&Al[cur][0] + (wm * 64 + t * 16 + lm) * 32 + q * 8);
#pragma unroll
    for (int t = 0; t < NJ; ++t)
      bfr[t] = *(const short8*)(&Bl[cur][0] + (wn * QN + t * 16 + lm) * 32 + q * 8);
#pragma unroll
    for (int i = 0; i < 4; ++i)
#pragma unroll
      for (int j = 0; j < NJ; ++j) acc[i][j] = MFMA16(af[i], bfr[j], acc[i][j]);
    __syncthreads();
    cur ^= 1;
  }

  if (EPI == 0) {
#pragma unroll
    for (int i = 0; i < 4; ++i) {
      int mb = m0 + wm * 64 + i * 16 + q * 4;  // multiple of 4 -> rg stays in one (b,l) row group
#pragma unroll
      for (int j = 0; j < NJ; ++j) {
        int n = n0 + wn * QN + j * 16 + lm;
        int which = n / 768;
        int r = n - which * 768;
        int h = r >> 6, d = r & 63;
        if (which == 2) {
          int b = mb >> 10, l = mb & 1023;  // mb..mb+3: same b, consecutive l
          ushort4 pk;
          pk.x = f2bf(acc[i][j][0]);
          pk.y = f2bf(acc[i][j][1]);
          pk.z = f2bf(acc[i][j][2]);
          pk.w = f2bf(acc[i][j][3]);
          *(ushort4*)(vt_ws + (size_t)((b * 12 + h) * 64 + d) * 1024 + l) = pk;
        } else {
          unsigned short* dst = (which == 0) ? q_ws : k_ws;
          float sc = (which == 0) ? 0.125f : 1.0f;  // fold attention scale into q
#pragma unroll
          for (int rg = 0; rg < 4; ++rg) {
            int m = mb + rg;
            int b = m >> 10, l = m & 1023;
            dst[(size_t)((b * 12 + h) * 1024 + l) * 64 + d] = f2bf(acc[i][j][rg] * sc);
          }
        }
      }
    }
  } else {
#pragma unroll
    for (int i = 0; i < 4; ++i) {
      int mb = m0 + wm * 64 + i * 16 + q * 4;
#pragma unroll
      for (int j = 0; j < NJ; ++j) {
        int n = n0 + wn * QN + j * 16 + lm;
        float bv = bias[n];
#pragma unroll
        for (int rg = 0; rg < 4; ++rg) {
          int m = mb + rg;
          __builtin_nontemporal_store(acc[i][j][rg] + bv, Cout + (size_t)m * N + n);
        }
      }
    }
  }
}

// ---------------- attention ----------------
// 1D grid 1536 (XCD-swizzled): 32 query rows per block, 512 threads = 8 waves.
// wave = (rowgrp = wave>>2, w4 = wave&3): rowgrp picks 16-row group, w4 picks 256-key
// span (QK^T) / 16-wide d-tile (PV).  Swapped QK^T: lane (q,lm) holds q-row
// rowgrp*16+lm, keys (w4*16+ct)*16 + q*4 + rg in acc[16][4] regs.
// Online softmax: exp vs wave-local max, single (mloc,ssum) publish, combine with
// e^(mloc-m) correction -> 2 barriers total.  out1 via nontemporal floatx4 stores.
__global__ __launch_bounds__(512, 4) void attn_mfma(
    const unsigned short* __restrict__ q_ws, const unsigned short* __restrict__ k_ws,
    const unsigned short* __restrict__ vt_ws, unsigned short* __restrict__ attn_o,
    float* __restrict__ out1) {
  constexpr int L = 1024, SW = 1032;  // stride: 16B-aligned rows (2064B = 516 banks, 4 mod 32)
  constexpr float LOG2E = 1.44269504f;
  __shared__ __align__(16) unsigned short S[32 * SW];
  __shared__ float stats[2][8][16];  // [mloc|ssum][wave][row-in-group]
  // bijective XCD swizzle: 1536 blocks = 8 XCDs x 192; each XCD owns 6 consecutive bh
  // (K/V working set 1.5 MB -> L2-resident instead of 8x L3 re-fetch).
  const int flat = blockIdx.x;
  const int swz = (flat & 7) * 192 + (flat >> 3);
  const int bh = swz >> 5, b = bh / 12, h = bh % 12;
  const int l0 = (swz & 31) * 32;
  const int tid = threadIdx.x, lane = tid & 63, wave = tid >> 6;
  const int q = lane >> 4, lm = lane & 15;
  const int rowgrp = wave >> 2, w4 = wave & 3;
  const int qrow = l0 + rowgrp * 16 + lm;  // this lane's query row

  const size_t qk_base = (size_t)bh * L * 64;

  // Q as B-fragment: B[n=q-row=lm][k=q*8+j]; q pre-scaled by 0.125
  const unsigned short* qr = q_ws + qk_base + (size_t)qrow * 64;
  short8 bq0 = *(const short8*)(qr + q * 8);
  short8 bq1 = *(const short8*)(qr + 32 + q * 8);

  // ---- swapped QK^T into registers (wave covers keys [w4*256, w4*256+256)) ----
  floatx4 acc[16];
  __builtin_amdgcn_s_setprio(1);
#pragma unroll
  for (int ct = 0; ct < 16; ++ct) {
    const unsigned short* kr = k_ws + qk_base + (size_t)((w4 * 16 + ct) * 16 + lm) * 64;
    short8 a0 = *(const short8*)(kr + q * 8);
    short8 a1 = *(const short8*)(kr + 32 + q * 8);
    floatx4 c = (floatx4){0.f, 0.f, 0.f, 0.f};
    c = MFMA16(a0, bq0, c);
    c = MFMA16(a1, bq1, c);
    acc[ct] = c;
  }
  __builtin_amdgcn_s_setprio(0);

  // ---- online register softmax: row = qrow, spread over 4 waves (same rowgrp) ----
  float mloc = -1e30f;
#pragma unroll
  for (int ct = 0; ct < 16; ++ct)
#pragma unroll
    for (int rg = 0; rg < 4; ++rg) mloc = fmaxf(mloc, acc[ct][rg]);
  mloc = fmaxf(mloc, __shfl_xor(mloc, 16));
  mloc = fmaxf(mloc, __shfl_xor(mloc, 32));

  float ssum = 0.f;
#pragma unroll
  for (int ct = 0; ct < 16; ++ct) {
#pragma unroll
    for (int rg = 0; rg < 4; ++rg) {
      float e = exp2f((acc[ct][rg] - mloc) * LOG2E);
      acc[ct][rg] = e;
      ssum += e;
    }
  }
  ssum += __shfl_xor(ssum, 16);
  ssum += __shfl_xor(ssum, 32);
  if (lane < 16) {
    stats[0][wave][lane] = mloc;
    stats[1][wave][lane] = ssum;
  }
  __syncthreads();  // B1: stats published

  const int wb = rowgrp * 4;
  float m0_ = stats[0][wb + 0][lm], m1_ = stats[0][wb + 1][lm];
  float m2_ = stats[0][wb + 2][lm], m3_ = stats[0][wb + 3][lm];
  float m = fmaxf(fmaxf(m0_, m1_), fmaxf(m2_, m3_));
  float sum = stats[1][wb + 0][lm] * exp2f((m0_ - m) * LOG2E)
            + stats[1][wb + 1][lm] * exp2f((m1_ - m) * LOG2E)
            + stats[1][wb + 2][lm] * exp2f((m2_ - m) * LOG2E)
            + stats[1][wb + 3][lm] * exp2f((m3_ - m) * LOG2E);
  float wscale = exp2f((mloc - m) * LOG2E) / sum;  // folds local-max correction + 1/sum

  // ---- write normalized S (bf16, for PV) + out1 (fp32, nt) straight from registers ----
  float* orow = out1 + (size_t)bh * L * L + (size_t)qrow * L + w4 * 256 + q * 4;
  unsigned short* srow = S + (rowgrp * 16 + lm) * SW + w4 * 256 + q * 4;
#pragma unroll
  for (int ct = 0; ct < 16; ++ct) {
    float p0 = acc[ct][0] * wscale, p1 = acc[ct][1] * wscale;
    float p2 = acc[ct][2] * wscale, p3 = acc[ct][3] * wscale;
    ushort4 pk;
    pk.x = f2bf(p0); pk.y = f2bf(p1); pk.z = f2bf(p2); pk.w = f2bf(p3);
    *(ushort4*)(srow + ct * 16) = pk;
    floatx4 pv = (floatx4){p0, p1, p2, p3};
    __builtin_nontemporal_store(pv, (floatx4*)(orow + ct * 16));
  }
  __syncthreads();  // B2: S ready

  // ---- PV: wave (rowgrp, w4) owns rows rowgrp*16.. x d-tile [w4*16, w4*16+16) ----
  {
    floatx4 pacc = (floatx4){0.f, 0.f, 0.f, 0.f};
    const unsigned short* vr = vt_ws + (size_t)(bh * 64 + w4 * 16 + lm) * 1024;
    const unsigned short* sbase = S + (rowgrp * 16 + lm) * SW;
    __builtin_amdgcn_s_setprio(1);
#pragma unroll 4
    for (int ks = 0; ks < 32; ++ks) {
      short8 af = *(const short8*)(sbase + ks * 32 + q * 8);  // one ds_read_b128
      short8 bv = *(const short8*)(vr + ks * 32 + q * 8);
      pacc = MFMA16(af, bv, pacc);
    }
    __builtin_amdgcn_s_setprio(0);
#pragma unroll
    for (int rg = 0; rg < 4; ++rg) {
      int row = rowgrp * 16 + q * 4 + rg;
      attn_o[(size_t)(b * 1024 + l0 + row) * 768 + h * 64 + w4 * 16 + lm] = f2bf(pacc[rg]);
    }
  }
}

extern "C" void kernel_launch(void* const* d_in, const int* in_sizes, int n_in,
                              void* d_out, int out_size, void* d_ws, size_t ws_size,
                              hipStream_t stream) {
  const float* x      = (const float*)d_in[0];  // [4,1024,768]
  const float* w_qkv  = (const float*)d_in[1];  // [2304,768]
  const float* w_proj = (const float*)d_in[2];  // [768,768]
  const float* b_proj = (const float*)d_in[3];  // [768]

  float* out0 = (float*)d_out;                   // [4096,768]
  float* out1 = out0 + (size_t)4096 * 768;       // [48,1024,1024]

  const size_t NX = (size_t)4096 * 768;   // 3,145,728
  const size_t NWQ = (size_t)2304 * 768;  // 1,769,472
  const size_t NWP = (size_t)768 * 768;   //   589,824
  const size_t NQ = (size_t)48 * 1024 * 64;

  unsigned short* x_bf   = (unsigned short*)d_ws;
  unsigned short* wq_bf  = x_bf + NX;
  unsigned short* wp_bf  = wq_bf + NWQ;
  unsigned short* q_ws   = wp_bf + NWP;
  unsigned short* k_ws   = q_ws + NQ;
  unsigned short* vt_ws  = k_ws + NQ;
  unsigned short* attn_o = vt_ws + NQ;   // [4096][768] bf16

  // 1) fused casts (dst regions contiguous from x_bf)
  cast3_kernel<<<dim3((NX + NWQ + NWP) / 1024), dim3(256), 0, stream>>>(x, w_qkv, w_proj, x_bf);

  // 2) qkv GEMM + scatter  (128x128 tiles, 576 blocks = 8 XCD x 72)
  gemm_bt<0, 128><<<dim3(576), dim3(256), 0, stream>>>(
      x_bf, wq_bf, nullptr, q_ws, k_ws, vt_ws, nullptr, 4096, 2304, 768, 18, 72);

  // 3) attention (1536 blocks = 8 XCD x 192, 512 threads)
  attn_mfma<<<dim3(1536), dim3(512), 0, stream>>>(q_ws, k_ws, vt_ws, attn_o, out1);

  // 4) proj GEMM + bias  (128x64 tiles, 384 blocks = 8 XCD x 48)
  gemm_bt<1, 64><<<dim3(384), dim3(256), 0, stream>>>(
      attn_o, wp_bf, b_proj, nullptr, nullptr, nullptr, out0, 4096, 768, 768, 12, 48);
}

// Round 6
// 340.614 us; speedup vs baseline: 1.0173x; 1.0173x over previous
//
#include <hip/hip_runtime.h>
#include <hip/hip_bf16.h>
#include <stdint.h>

// B=4, L=1024, C=768, H=12, D=64.  All inputs/outputs fp32.
// Pipeline (all-MFMA bf16, fp32 accumulate):
//   c1: cast x, w_qkv, w_proj -> bf16 ws (single fused launch)
//   k1: qkv GEMM  [4096x768]@[2304x768]^T (128x128 tile, dbuf prefetch, XCD-swizzled)
//       -> scatter q(pre*0.125),k [bh][l][d], v^T [bh][d][l]  (bf16)
//   k2: attention per (bh, 16 rows): 4 waves, swapped QK^T -> online register softmax
//       (1 publish, 2 barriers) -> out1 fp32 nt-stores + normalized bf16 S in LDS
//       -> PV MFMA (2 independent chains) -> attn_o.  XCD-swizzled 1D grid.
//   k3: proj GEMM  [4096x768]@[768x768]^T + bias (128x64 tile, XCD-swizzled) -> out0 fp32

typedef __attribute__((ext_vector_type(8))) short short8;
typedef __attribute__((ext_vector_type(4))) float floatx4;

#define MFMA16(A_, B_, C_) __builtin_amdgcn_mfma_f32_16x16x32_bf16((A_), (B_), (C_), 0, 0, 0)

__device__ __forceinline__ unsigned short f2bf(float f) {
  unsigned u = __builtin_bit_cast(unsigned, f);
  u += 0x7FFFu + ((u >> 16) & 1u);   // round-to-nearest-even
  return (unsigned short)(u >> 16);
}
__device__ __forceinline__ float bf2f(unsigned short u) {
  return __builtin_bit_cast(float, (unsigned)u << 16);
}

// ---------------- fused cast fp32 -> bf16 (x, w_qkv, w_proj; contiguous dst) ----------------
__global__ __launch_bounds__(256) void cast3_kernel(const float* __restrict__ x,
                                                    const float* __restrict__ wq,
                                                    const float* __restrict__ wp,
                                                    unsigned short* __restrict__ dst) {
  const int NX = 3145728, NWQ = 1769472;  // region boundaries are block-aligned
  int i = (blockIdx.x * 256 + threadIdx.x) * 4;
  const float* src;
  int off;
  if (i < NX) { src = x; off = i; }
  else if (i < NX + NWQ) { src = wq; off = i - NX; }
  else { src = wp; off = i - NX - NWQ; }
  float4 v = *(const float4*)(src + off);
  ushort4 o;
  o.x = f2bf(v.x); o.y = f2bf(v.y); o.z = f2bf(v.z); o.w = f2bf(v.w);
  *(ushort4*)(dst + i) = o;
}

// ---------------- bf16 MFMA GEMM: C[M][N] = A[M][K] @ Bm[N][K]^T ----------------
// tile 128xBN, BK=32, 256 threads = 4 waves.  Wave (wm,wn) owns a 64x(BN/2) quadrant.
// Double-buffered LDS; next K-tile's global_load_lds issued BEFORE compute of current.
// 1D grid, bijective XCD swizzle (nb = 8*chunk): each XCD owns `chunk` consecutive
// tiles (row-major) -> A-panels + B reuse within one XCD L2.
// EPI 0: qkv scatter epilogue (BN=128 only).  EPI 1: fp32 C + bias epilogue (nt store).
template <int EPI, int BN>
__global__ __launch_bounds__(256) void gemm_bt(
    const unsigned short* __restrict__ A, const unsigned short* __restrict__ Bm,
    const float* __restrict__ bias,
    unsigned short* __restrict__ q_ws, unsigned short* __restrict__ k_ws,
    unsigned short* __restrict__ vt_ws, float* __restrict__ Cout,
    int M, int N, int K, int nbx, int chunk) {
  constexpr int NJ = BN / 32;  // N-frags per wave (4 or 2)
  constexpr int QN = BN / 2;   // wave quadrant N-size (64 or 32)
  __shared__ __align__(16) unsigned short Al[2][128 * 32];
  __shared__ __align__(16) unsigned short Bl[2][BN * 32];
  const int tid = threadIdx.x;
  const int lane = tid & 63, wave = tid >> 6;
  const int q = lane >> 4, lm = lane & 15;
  const int wm = wave >> 1, wn = wave & 1;
  const int flat = blockIdx.x;
  const int swz = (flat & 7) * chunk + (flat >> 3);
  const int m0 = (swz / nbx) * 128, n0 = (swz % nbx) * BN;

  floatx4 acc[4][NJ];
#pragma unroll
  for (int i = 0; i < 4; ++i)
#pragma unroll
    for (int j = 0; j < NJ; ++j) acc[i][j] = (floatx4){0.f, 0.f, 0.f, 0.f};

  auto stage = [&](int k0, int buf) {
#pragma unroll
    for (int it = 0; it < 2; ++it) {
      int idx = tid + it * 256;
      int row = idx >> 2, ch = idx & 3;
      const unsigned short* ga = A + (size_t)(m0 + row) * K + k0 + ch * 8;
      __builtin_amdgcn_global_load_lds(
          (const __attribute__((address_space(1))) unsigned int*)ga,
          (__attribute__((address_space(3))) unsigned int*)(&Al[buf][0] + idx * 8), 16, 0, 0);
    }
#pragma unroll
    for (int it = 0; it < BN / 64; ++it) {
      int idx = tid + it * 256;
      int row = idx >> 2, ch = idx & 3;
      const unsigned short* gb = Bm + (size_t)(n0 + row) * K + k0 + ch * 8;
      __builtin_amdgcn_global_load_lds(
          (const __attribute__((address_space(1))) unsigned int*)gb,
          (__attribute__((address_space(3))) unsigned int*)(&Bl[buf][0] + idx * 8), 16, 0, 0);
    }
  };

  stage(0, 0);
  __syncthreads();
  int cur = 0;
  for (int k0 = 0; k0 < K; k0 += 32) {
    if (k0 + 32 < K) stage(k0 + 32, cur ^ 1);  // prefetch next tile, in flight during MFMA
    short8 af[4], bfr[NJ];
#pragma unroll
    for (int t = 0; t < 4; ++t)
      af[t] = *(const short8*)(&Al[cur][0] + (wm * 64 + t * 16 + lm) * 32 + q * 8);
#pragma unroll
    for (int t = 0; t < NJ; ++t)
      bfr[t] = *(const short8*)(&Bl[cur][0] + (wn * QN + t * 16 + lm) * 32 + q * 8);
#pragma unroll
    for (int i = 0; i < 4; ++i)
#pragma unroll
      for (int j = 0; j < NJ; ++j) acc[i][j] = MFMA16(af[i], bfr[j], acc[i][j]);
    __syncthreads();
    cur ^= 1;
  }

  if (EPI == 0) {
#pragma unroll
    for (int i = 0; i < 4; ++i) {
      int mb = m0 + wm * 64 + i * 16 + q * 4;  // multiple of 4 -> rg stays in one (b,l) row group
#pragma unroll
      for (int j = 0; j < NJ; ++j) {
        int n = n0 + wn * QN + j * 16 + lm;
        int which = n / 768;
        int r = n - which * 768;
        int h = r >> 6, d = r & 63;
        if (which == 2) {
          int b = mb >> 10, l = mb & 1023;  // mb..mb+3: same b, consecutive l
          ushort4 pk;
          pk.x = f2bf(acc[i][j][0]);
          pk.y = f2bf(acc[i][j][1]);
          pk.z = f2bf(acc[i][j][2]);
          pk.w = f2bf(acc[i][j][3]);
          *(ushort4*)(vt_ws + (size_t)((b * 12 + h) * 64 + d) * 1024 + l) = pk;
        } else {
          unsigned short* dst = (which == 0) ? q_ws : k_ws;
          float sc = (which == 0) ? 0.125f : 1.0f;  // fold attention scale into q
#pragma unroll
          for (int rg = 0; rg < 4; ++rg) {
            int m = mb + rg;
            int b = m >> 10, l = m & 1023;
            dst[(size_t)((b * 12 + h) * 1024 + l) * 64 + d] = f2bf(acc[i][j][rg] * sc);
          }
        }
      }
    }
  } else {
#pragma unroll
    for (int i = 0; i < 4; ++i) {
      int mb = m0 + wm * 64 + i * 16 + q * 4;
#pragma unroll
      for (int j = 0; j < NJ; ++j) {
        int n = n0 + wn * QN + j * 16 + lm;
        float bv = bias[n];
#pragma unroll
        for (int rg = 0; rg < 4; ++rg) {
          int m = mb + rg;
          __builtin_nontemporal_store(acc[i][j][rg] + bv, Cout + (size_t)m * N + n);
        }
      }
    }
  }
}

// ---------------- attention ----------------
// 1D grid 3072 (XCD-swizzled): 16 query rows per block, 256 threads = 4 waves.
// Swapped QK^T: C = MFMA(K_frag, Q_frag) -> lane (q,lm) holds q-row lm, keys
// (wave*16+ct)*16 + q*4 + rg => full row slice lives in acc[16][4] regs.
// Online softmax: exp vs wave-local max, single (mloc,ssum) publish, combine with
// e^(mloc-m) correction -> 2 barriers total.  out1 via nt floatx4 stores.
// PV uses two independent MFMA accumulator chains (latency, not throughput, bound).
__global__ __launch_bounds__(256) void attn_mfma(
    const unsigned short* __restrict__ q_ws, const unsigned short* __restrict__ k_ws,
    const unsigned short* __restrict__ vt_ws, unsigned short* __restrict__ attn_o,
    float* __restrict__ out1) {
  constexpr int L = 1024, SW = 1032;  // stride: 16B-aligned rows (2064B = 516 banks, 4 mod 32)
  constexpr float LOG2E = 1.44269504f;
  __shared__ __align__(16) unsigned short S[16 * SW];
  __shared__ float stats[2][4][16];  // [mloc|ssum][wave][row]
  // bijective XCD swizzle: 3072 blocks = 8 XCDs x 384; each XCD owns 6 consecutive bh
  // (K/V working set 1.5 MB -> L2-resident instead of 8x L3 re-fetch).
  const int flat = blockIdx.x;
  const int swz = (flat & 7) * 384 + (flat >> 3);
  const int bh = swz >> 6, b = bh / 12, h = bh % 12;
  const int l0 = (swz & 63) * 16;
  const int tid = threadIdx.x, lane = tid & 63, wave = tid >> 6;
  const int q = lane >> 4, lm = lane & 15;

  const size_t qk_base = (size_t)bh * L * 64;

  // Q as B-fragment: B[n=q-row=lm][k=q*8+j]; q pre-scaled by 0.125
  const unsigned short* qr = q_ws + qk_base + (size_t)(l0 + lm) * 64;
  short8 bq0 = *(const short8*)(qr + q * 8);
  short8 bq1 = *(const short8*)(qr + 32 + q * 8);

  // ---- swapped QK^T into registers ----
  floatx4 acc[16];
  __builtin_amdgcn_s_setprio(1);
#pragma unroll
  for (int ct = 0; ct < 16; ++ct) {
    const unsigned short* kr = k_ws + qk_base + (size_t)((wave * 16 + ct) * 16 + lm) * 64;
    short8 a0 = *(const short8*)(kr + q * 8);
    short8 a1 = *(const short8*)(kr + 32 + q * 8);
    floatx4 c = (floatx4){0.f, 0.f, 0.f, 0.f};
    c = MFMA16(a0, bq0, c);
    c = MFMA16(a1, bq1, c);
    acc[ct] = c;
  }
  __builtin_amdgcn_s_setprio(0);

  // ---- online register softmax: row r = lm ----
  float mloc = -1e30f;
#pragma unroll
  for (int ct = 0; ct < 16; ++ct)
#pragma unroll
    for (int rg = 0; rg < 4; ++rg) mloc = fmaxf(mloc, acc[ct][rg]);
  mloc = fmaxf(mloc, __shfl_xor(mloc, 16));
  mloc = fmaxf(mloc, __shfl_xor(mloc, 32));

  float ssum = 0.f;
#pragma unroll
  for (int ct = 0; ct < 16; ++ct) {
#pragma unroll
    for (int rg = 0; rg < 4; ++rg) {
      float e = exp2f((acc[ct][rg] - mloc) * LOG2E);
      acc[ct][rg] = e;
      ssum += e;
    }
  }
  ssum += __shfl_xor(ssum, 16);
  ssum += __shfl_xor(ssum, 32);
  if (lane < 16) {
    stats[0][wave][lane] = mloc;
    stats[1][wave][lane] = ssum;
  }
  __syncthreads();  // B1: stats published

  float m0_ = stats[0][0][lm], m1_ = stats[0][1][lm];
  float m2_ = stats[0][2][lm], m3_ = stats[0][3][lm];
  float m = fmaxf(fmaxf(m0_, m1_), fmaxf(m2_, m3_));
  float sum = stats[1][0][lm] * exp2f((m0_ - m) * LOG2E)
            + stats[1][1][lm] * exp2f((m1_ - m) * LOG2E)
            + stats[1][2][lm] * exp2f((m2_ - m) * LOG2E)
            + stats[1][3][lm] * exp2f((m3_ - m) * LOG2E);
  float wscale = exp2f((mloc - m) * LOG2E) / sum;  // folds local-max correction + 1/sum

  // ---- write normalized S (bf16, for PV) + out1 (fp32, nt) straight from registers ----
  float* orow = out1 + (size_t)bh * L * L + (size_t)(l0 + lm) * L + wave * 256 + q * 4;
  unsigned short* srow = S + lm * SW + wave * 256 + q * 4;
#pragma unroll
  for (int ct = 0; ct < 16; ++ct) {
    float p0 = acc[ct][0] * wscale, p1 = acc[ct][1] * wscale;
    float p2 = acc[ct][2] * wscale, p3 = acc[ct][3] * wscale;
    ushort4 pk;
    pk.x = f2bf(p0); pk.y = f2bf(p1); pk.z = f2bf(p2); pk.w = f2bf(p3);
    *(ushort4*)(srow + ct * 16) = pk;
    floatx4 pv = (floatx4){p0, p1, p2, p3};
    __builtin_nontemporal_store(pv, (floatx4*)(orow + ct * 16));
  }
  __syncthreads();  // B2: S ready

  // ---- PV: wave owns d-tile [wave*16, wave*16+16); S pre-normalized.
  //      Two independent accumulator chains (even/odd ks) to break MFMA latency chain.
  {
    floatx4 pacc0 = (floatx4){0.f, 0.f, 0.f, 0.f};
    floatx4 pacc1 = (floatx4){0.f, 0.f, 0.f, 0.f};
    const unsigned short* vr = vt_ws + (size_t)(bh * 64 + wave * 16 + lm) * 1024;
    const unsigned short* sbase = S + lm * SW;
    __builtin_amdgcn_s_setprio(1);
#pragma unroll 4
    for (int ks = 0; ks < 32; ks += 2) {
      short8 af0 = *(const short8*)(sbase + ks * 32 + q * 8);        // ds_read_b128
      short8 bv0 = *(const short8*)(vr + ks * 32 + q * 8);
      pacc0 = MFMA16(af0, bv0, pacc0);
      short8 af1 = *(const short8*)(sbase + (ks + 1) * 32 + q * 8);
      short8 bv1 = *(const short8*)(vr + (ks + 1) * 32 + q * 8);
      pacc1 = MFMA16(af1, bv1, pacc1);
    }
    __builtin_amdgcn_s_setprio(0);
    floatx4 pacc = pacc0 + pacc1;
#pragma unroll
    for (int rg = 0; rg < 4; ++rg) {
      int row = q * 4 + rg;
      attn_o[(size_t)(b * 1024 + l0 + row) * 768 + h * 64 + wave * 16 + lm] = f2bf(pacc[rg]);
    }
  }
}

extern "C" void kernel_launch(void* const* d_in, const int* in_sizes, int n_in,
                              void* d_out, int out_size, void* d_ws, size_t ws_size,
                              hipStream_t stream) {
  const float* x      = (const float*)d_in[0];  // [4,1024,768]
  const float* w_qkv  = (const float*)d_in[1];  // [2304,768]
  const float* w_proj = (const float*)d_in[2];  // [768,768]
  const float* b_proj = (const float*)d_in[3];  // [768]

  float* out0 = (float*)d_out;                   // [4096,768]
  float* out1 = out0 + (size_t)4096 * 768;       // [48,1024,1024]

  const size_t NX = (size_t)4096 * 768;   // 3,145,728
  const size_t NWQ = (size_t)2304 * 768;  // 1,769,472
  const size_t NWP = (size_t)768 * 768;   //   589,824
  const size_t NQ = (size_t)48 * 1024 * 64;

  unsigned short* x_bf   = (unsigned short*)d_ws;
  unsigned short* wq_bf  = x_bf + NX;
  unsigned short* wp_bf  = wq_bf + NWQ;
  unsigned short* q_ws   = wp_bf + NWP;
  unsigned short* k_ws   = q_ws + NQ;
  unsigned short* vt_ws  = k_ws + NQ;
  unsigned short* attn_o = vt_ws + NQ;   // [4096][768] bf16

  // 1) fused casts (dst regions contiguous from x_bf)
  cast3_kernel<<<dim3((NX + NWQ + NWP) / 1024), dim3(256), 0, stream>>>(x, w_qkv, w_proj, x_bf);

  // 2) qkv GEMM + scatter  (128x128 tiles, 576 blocks = 8 XCD x 72)
  gemm_bt<0, 128><<<dim3(576), dim3(256), 0, stream>>>(
      x_bf, wq_bf, nullptr, q_ws, k_ws, vt_ws, nullptr, 4096, 2304, 768, 18, 72);

  // 3) attention (3072 blocks = 8 XCD x 384, 256 threads)
  attn_mfma<<<dim3(3072), dim3(256), 0, stream>>>(q_ws, k_ws, vt_ws, attn_o, out1);

  // 4) proj GEMM + bias  (128x64 tiles, 384 blocks = 8 XCD x 48)
  gemm_bt<1, 64><<<dim3(384), dim3(256), 0, stream>>>(
      attn_o, wp_bf, b_proj, nullptr, nullptr, nullptr, out0, 4096, 768, 768, 12, 48);
}

// Round 8
// 333.040 us; speedup vs baseline: 1.0404x; 1.0227x over previous
//
#include <hip/hip_runtime.h>
#include <hip/hip_bf16.h>
#include <stdint.h>

// B=4, L=1024, C=768, H=12, D=64.  All inputs/outputs fp32.
// Pipeline (all-MFMA bf16, fp32 accumulate):
//   c1: cast x, w_qkv, w_proj -> bf16 ws (single fused launch)
//   k1: qkv GEMM  [4096x768]@[2304x768]^T (128x128 tile, dbuf prefetch, XCD-swizzled)
//       -> scatter q(pre*0.125),k [bh][l][d], v^T [bh][d][l]  (bf16)
//   k2: attention per (bh, 16 rows): 4 waves, swapped QK^T -> online register softmax
//       (1 publish, 2 barriers) -> normalized bf16 S in LDS -> out1 fp32 COALESCED
//       from LDS (1KB/wave-store) -> PV MFMA (2 chains) -> attn_o.  XCD-swizzled grid.
//   k3: proj GEMM  [4096x768]@[768x768]^T + bias (128x64 tile, XCD-swizzled) -> out0 fp32

typedef __attribute__((ext_vector_type(8))) short short8;
typedef __attribute__((ext_vector_type(4))) float floatx4;

#define MFMA16(A_, B_, C_) __builtin_amdgcn_mfma_f32_16x16x32_bf16((A_), (B_), (C_), 0, 0, 0)

__device__ __forceinline__ unsigned short f2bf(float f) {
  unsigned u = __builtin_bit_cast(unsigned, f);
  u += 0x7FFFu + ((u >> 16) & 1u);   // round-to-nearest-even
  return (unsigned short)(u >> 16);
}
__device__ __forceinline__ float bf2f(unsigned short u) {
  return __builtin_bit_cast(float, (unsigned)u << 16);
}

// ---------------- fused cast fp32 -> bf16 (x, w_qkv, w_proj; contiguous dst) ----------------
__global__ __launch_bounds__(256) void cast3_kernel(const float* __restrict__ x,
                                                    const float* __restrict__ wq,
                                                    const float* __restrict__ wp,
                                                    unsigned short* __restrict__ dst) {
  const int NX = 3145728, NWQ = 1769472;  // region boundaries are block-aligned
  int i = (blockIdx.x * 256 + threadIdx.x) * 4;
  const float* src;
  int off;
  if (i < NX) { src = x; off = i; }
  else if (i < NX + NWQ) { src = wq; off = i - NX; }
  else { src = wp; off = i - NX - NWQ; }
  float4 v = *(const float4*)(src + off);
  ushort4 o;
  o.x = f2bf(v.x); o.y = f2bf(v.y); o.z = f2bf(v.z); o.w = f2bf(v.w);
  *(ushort4*)(dst + i) = o;
}

// ---------------- bf16 MFMA GEMM: C[M][N] = A[M][K] @ Bm[N][K]^T ----------------
// tile 128xBN, BK=32, 256 threads = 4 waves.  Wave (wm,wn) owns a 64x(BN/2) quadrant.
// Double-buffered LDS; next K-tile's global_load_lds issued BEFORE compute of current.
// 1D grid, bijective XCD swizzle (nb = 8*chunk): each XCD owns `chunk` consecutive
// tiles (row-major) -> A-panels + B reuse within one XCD L2.
// EPI 0: qkv scatter epilogue (BN=128 only).  EPI 1: fp32 C + bias epilogue (nt store).
template <int EPI, int BN>
__global__ __launch_bounds__(256) void gemm_bt(
    const unsigned short* __restrict__ A, const unsigned short* __restrict__ Bm,
    const float* __restrict__ bias,
    unsigned short* __restrict__ q_ws, unsigned short* __restrict__ k_ws,
    unsigned short* __restrict__ vt_ws, float* __restrict__ Cout,
    int M, int N, int K, int nbx, int chunk) {
  constexpr int NJ = BN / 32;  // N-frags per wave (4 or 2)
  constexpr int QN = BN / 2;   // wave quadrant N-size (64 or 32)
  __shared__ __align__(16) unsigned short Al[2][128 * 32];
  __shared__ __align__(16) unsigned short Bl[2][BN * 32];
  const int tid = threadIdx.x;
  const int lane = tid & 63, wave = tid >> 6;
  const int q = lane >> 4, lm = lane & 15;
  const int wm = wave >> 1, wn = wave & 1;
  const int flat = blockIdx.x;
  const int swz = (flat & 7) * chunk + (flat >> 3);
  const int m0 = (swz / nbx) * 128, n0 = (swz % nbx) * BN;

  floatx4 acc[4][NJ];
#pragma unroll
  for (int i = 0; i < 4; ++i)
#pragma unroll
    for (int j = 0; j < NJ; ++j) acc[i][j] = (floatx4){0.f, 0.f, 0.f, 0.f};

  auto stage = [&](int k0, int buf) {
#pragma unroll
    for (int it = 0; it < 2; ++it) {
      int idx = tid + it * 256;
      int row = idx >> 2, ch = idx & 3;
      const unsigned short* ga = A + (size_t)(m0 + row) * K + k0 + ch * 8;
      __builtin_amdgcn_global_load_lds(
          (const __attribute__((address_space(1))) unsigned int*)ga,
          (__attribute__((address_space(3))) unsigned int*)(&Al[buf][0] + idx * 8), 16, 0, 0);
    }
#pragma unroll
    for (int it = 0; it < BN / 64; ++it) {
      int idx = tid + it * 256;
      int row = idx >> 2, ch = idx & 3;
      const unsigned short* gb = Bm + (size_t)(n0 + row) * K + k0 + ch * 8;
      __builtin_amdgcn_global_load_lds(
          (const __attribute__((address_space(1))) unsigned int*)gb,
          (__attribute__((address_space(3))) unsigned int*)(&Bl[buf][0] + idx * 8), 16, 0, 0);
    }
  };

  stage(0, 0);
  __syncthreads();
  int cur = 0;
  for (int k0 = 0; k0 < K; k0 += 32) {
    if (k0 + 32 < K) stage(k0 + 32, cur ^ 1);  // prefetch next tile, in flight during MFMA
    short8 af[4], bfr[NJ];
#pragma unroll
    for (int t = 0; t < 4; ++t)
      af[t] = *(const short8*)(&Al[cur][0] + (wm * 64 + t * 16 + lm) * 32 + q * 8);
#pragma unroll
    for (int t = 0; t < NJ; ++t)
      bfr[t] = *(const short8*)(&Bl[cur][0] + (wn * QN + t * 16 + lm) * 32 + q * 8);
#pragma unroll
    for (int i = 0; i < 4; ++i)
#pragma unroll
      for (int j = 0; j < NJ; ++j) acc[i][j] = MFMA16(af[i], bfr[j], acc[i][j]);
    __syncthreads();
    cur ^= 1;
  }

  if (EPI == 0) {
#pragma unroll
    for (int i = 0; i < 4; ++i) {
      int mb = m0 + wm * 64 + i * 16 + q * 4;  // multiple of 4 -> rg stays in one (b,l) row group
#pragma unroll
      for (int j = 0; j < NJ; ++j) {
        int n = n0 + wn * QN + j * 16 + lm;
        int which = n / 768;
        int r = n - which * 768;
        int h = r >> 6, d = r & 63;
        if (which == 2) {
          int b = mb >> 10, l = mb & 1023;  // mb..mb+3: same b, consecutive l
          ushort4 pk;
          pk.x = f2bf(acc[i][j][0]);
          pk.y = f2bf(acc[i][j][1]);
          pk.z = f2bf(acc[i][j][2]);
          pk.w = f2bf(acc[i][j][3]);
          *(ushort4*)(vt_ws + (size_t)((b * 12 + h) * 64 + d) * 1024 + l) = pk;
        } else {
          unsigned short* dst = (which == 0) ? q_ws : k_ws;
          float sc = (which == 0) ? 0.125f : 1.0f;  // fold attention scale into q
#pragma unroll
          for (int rg = 0; rg < 4; ++rg) {
            int m = mb + rg;
            int b = m >> 10, l = m & 1023;
            dst[(size_t)((b * 12 + h) * 1024 + l) * 64 + d] = f2bf(acc[i][j][rg] * sc);
          }
        }
      }
    }
  } else {
#pragma unroll
    for (int i = 0; i < 4; ++i) {
      int mb = m0 + wm * 64 + i * 16 + q * 4;
#pragma unroll
      for (int j = 0; j < NJ; ++j) {
        int n = n0 + wn * QN + j * 16 + lm;
        float bv = bias[n];
#pragma unroll
        for (int rg = 0; rg < 4; ++rg) {
          int m = mb + rg;
          __builtin_nontemporal_store(acc[i][j][rg] + bv, Cout + (size_t)m * N + n);
        }
      }
    }
  }
}

// ---------------- attention ----------------
// 1D grid 3072 (XCD-swizzled): 16 query rows per block, 256 threads = 4 waves.
// Swapped QK^T: C = MFMA(K_frag, Q_frag) -> lane (q,lm) holds q-row lm, keys
// (wave*16+ct)*16 + q*4 + rg => full row slice lives in acc[16][4] regs.
// Online softmax: exp vs wave-local max, single (mloc,ssum) publish, combine with
// e^(mloc-m) correction -> 2 barriers total.
// out1 written COALESCED from LDS S (thread t -> 4 consecutive cols of one row:
// each wave stores 1KB contiguous per instr, vs 16x64B fragments register-order).
// PV uses two independent MFMA accumulator chains.
__global__ __launch_bounds__(256) void attn_mfma(
    const unsigned short* __restrict__ q_ws, const unsigned short* __restrict__ k_ws,
    const unsigned short* __restrict__ vt_ws, unsigned short* __restrict__ attn_o,
    float* __restrict__ out1) {
  constexpr int L = 1024, SW = 1032;  // stride: 16B-aligned rows (2064B = 516 banks, 4 mod 32)
  constexpr float LOG2E = 1.44269504f;
  __shared__ __align__(16) unsigned short S[16 * SW];
  __shared__ float stats[2][4][16];  // [mloc|ssum][wave][row]
  // bijective XCD swizzle: 3072 blocks = 8 XCDs x 384; each XCD owns 6 consecutive bh
  // (K/V working set 1.5 MB -> L2-resident instead of 8x L3 re-fetch).
  const int flat = blockIdx.x;
  const int swz = (flat & 7) * 384 + (flat >> 3);
  const int bh = swz >> 6, b = bh / 12, h = bh % 12;
  const int l0 = (swz & 63) * 16;
  const int tid = threadIdx.x, lane = tid & 63, wave = tid >> 6;
  const int q = lane >> 4, lm = lane & 15;

  const size_t qk_base = (size_t)bh * L * 64;

  // Q as B-fragment: B[n=q-row=lm][k=q*8+j]; q pre-scaled by 0.125
  const unsigned short* qr = q_ws + qk_base + (size_t)(l0 + lm) * 64;
  short8 bq0 = *(const short8*)(qr + q * 8);
  short8 bq1 = *(const short8*)(qr + 32 + q * 8);

  // ---- swapped QK^T into registers ----
  floatx4 acc[16];
  __builtin_amdgcn_s_setprio(1);
#pragma unroll
  for (int ct = 0; ct < 16; ++ct) {
    const unsigned short* kr = k_ws + qk_base + (size_t)((wave * 16 + ct) * 16 + lm) * 64;
    short8 a0 = *(const short8*)(kr + q * 8);
    short8 a1 = *(const short8*)(kr + 32 + q * 8);
    floatx4 c = (floatx4){0.f, 0.f, 0.f, 0.f};
    c = MFMA16(a0, bq0, c);
    c = MFMA16(a1, bq1, c);
    acc[ct] = c;
  }
  __builtin_amdgcn_s_setprio(0);

  // ---- online register softmax: row r = lm ----
  float mloc = -1e30f;
#pragma unroll
  for (int ct = 0; ct < 16; ++ct)
#pragma unroll
    for (int rg = 0; rg < 4; ++rg) mloc = fmaxf(mloc, acc[ct][rg]);
  mloc = fmaxf(mloc, __shfl_xor(mloc, 16));
  mloc = fmaxf(mloc, __shfl_xor(mloc, 32));

  float ssum = 0.f;
#pragma unroll
  for (int ct = 0; ct < 16; ++ct) {
#pragma unroll
    for (int rg = 0; rg < 4; ++rg) {
      float e = exp2f((acc[ct][rg] - mloc) * LOG2E);
      acc[ct][rg] = e;
      ssum += e;
    }
  }
  ssum += __shfl_xor(ssum, 16);
  ssum += __shfl_xor(ssum, 32);
  if (lane < 16) {
    stats[0][wave][lane] = mloc;
    stats[1][wave][lane] = ssum;
  }
  __syncthreads();  // B1: stats published

  float m0_ = stats[0][0][lm], m1_ = stats[0][1][lm];
  float m2_ = stats[0][2][lm], m3_ = stats[0][3][lm];
  float m = fmaxf(fmaxf(m0_, m1_), fmaxf(m2_, m3_));
  float sum = stats[1][0][lm] * exp2f((m0_ - m) * LOG2E)
            + stats[1][1][lm] * exp2f((m1_ - m) * LOG2E)
            + stats[1][2][lm] * exp2f((m2_ - m) * LOG2E)
            + stats[1][3][lm] * exp2f((m3_ - m) * LOG2E);
  float wscale = exp2f((mloc - m) * LOG2E) / sum;  // folds local-max correction + 1/sum

  // ---- write normalized S (bf16) to LDS straight from registers ----
  unsigned short* srow = S + lm * SW + wave * 256 + q * 4;
#pragma unroll
  for (int ct = 0; ct < 16; ++ct) {
    ushort4 pk;
    pk.x = f2bf(acc[ct][0] * wscale);
    pk.y = f2bf(acc[ct][1] * wscale);
    pk.z = f2bf(acc[ct][2] * wscale);
    pk.w = f2bf(acc[ct][3] * wscale);
    *(ushort4*)(srow + ct * 16) = pk;
  }
  __syncthreads();  // B2: S ready

  // ---- out1 coalesced from LDS: thread t -> row r, cols t*4..t*4+3 (1KB/wave-store) ----
  {
    float* obase = out1 + (size_t)bh * L * L + (size_t)l0 * L;
    const int c0 = tid * 4;
#pragma unroll 4
    for (int r = 0; r < 16; ++r) {
      ushort4 pk = *(const ushort4*)(S + r * SW + c0);
      floatx4 pv = (floatx4){bf2f(pk.x), bf2f(pk.y), bf2f(pk.z), bf2f(pk.w)};
      __builtin_nontemporal_store(pv, (floatx4*)(obase + (size_t)r * L + c0));
    }
  }

  // ---- PV: wave owns d-tile [wave*16, wave*16+16); S pre-normalized.
  //      Two independent accumulator chains (even/odd ks) to break MFMA latency chain.
  {
    floatx4 pacc0 = (floatx4){0.f, 0.f, 0.f, 0.f};
    floatx4 pacc1 = (floatx4){0.f, 0.f, 0.f, 0.f};
    const unsigned short* vr = vt_ws + (size_t)(bh * 64 + wave * 16 + lm) * 1024;
    const unsigned short* sbase = S + lm * SW;
    __builtin_amdgcn_s_setprio(1);
#pragma unroll 4
    for (int ks = 0; ks < 32; ks += 2) {
      short8 af0 = *(const short8*)(sbase + ks * 32 + q * 8);        // ds_read_b128
      short8 bv0 = *(const short8*)(vr + ks * 32 + q * 8);
      pacc0 = MFMA16(af0, bv0, pacc0);
      short8 af1 = *(const short8*)(sbase + (ks + 1) * 32 + q * 8);
      short8 bv1 = *(const short8*)(vr + (ks + 1) * 32 + q * 8);
      pacc1 = MFMA16(af1, bv1, pacc1);
    }
    __builtin_amdgcn_s_setprio(0);
    floatx4 pacc = pacc0 + pacc1;
#pragma unroll
    for (int rg = 0; rg < 4; ++rg) {
      int row = q * 4 + rg;
      attn_o[(size_t)(b * 1024 + l0 + row) * 768 + h * 64 + wave * 16 + lm] = f2bf(pacc[rg]);
    }
  }
}

extern "C" void kernel_launch(void* const* d_in, const int* in_sizes, int n_in,
                              void* d_out, int out_size, void* d_ws, size_t ws_size,
                              hipStream_t stream) {
  const float* x      = (const float*)d_in[0];  // [4,1024,768]
  const float* w_qkv  = (const float*)d_in[1];  // [2304,768]
  const float* w_proj = (const float*)d_in[2];  // [768,768]
  const float* b_proj = (const float*)d_in[3];  // [768]

  float* out0 = (float*)d_out;                   // [4096,768]
  float* out1 = out0 + (size_t)4096 * 768;       // [48,1024,1024]

  const size_t NX = (size_t)4096 * 768;   // 3,145,728
  const size_t NWQ = (size_t)2304 * 768;  // 1,769,472
  const size_t NWP = (size_t)768 * 768;   //   589,824
  const size_t NQ = (size_t)48 * 1024 * 64;

  unsigned short* x_bf   = (unsigned short*)d_ws;
  unsigned short* wq_bf  = x_bf + NX;
  unsigned short* wp_bf  = wq_bf + NWQ;
  unsigned short* q_ws   = wp_bf + NWP;
  unsigned short* k_ws   = q_ws + NQ;
  unsigned short* vt_ws  = k_ws + NQ;
  unsigned short* attn_o = vt_ws + NQ;   // [4096][768] bf16

  // 1) fused casts (dst regions contiguous from x_bf)
  cast3_kernel<<<dim3((NX + NWQ + NWP) / 1024), dim3(256), 0, stream>>>(x, w_qkv, w_proj, x_bf);

  // 2) qkv GEMM + scatter  (128x128 tiles, 576 blocks = 8 XCD x 72)
  gemm_bt<0, 128><<<dim3(576), dim3(256), 0, stream>>>(
      x_bf, wq_bf, nullptr, q_ws, k_ws, vt_ws, nullptr, 4096, 2304, 768, 18, 72);

  // 3) attention (3072 blocks = 8 XCD x 384, 256 threads)
  attn_mfma<<<dim3(3072), dim3(256), 0, stream>>>(q_ws, k_ws, vt_ws, attn_o, out1);

  // 4) proj GEMM + bias  (128x64 tiles, 384 blocks = 8 XCD x 48)
  gemm_bt<1, 64><<<dim3(384), dim3(256), 0, stream>>>(
      attn_o, wp_bf, b_proj, nullptr, nullptr, nullptr, out0, 4096, 768, 768, 12, 48);
}